// Round 17
// baseline (343.146 us; speedup 1.0000x reference)
//
#include <hip/hip_runtime.h>
#include <math.h>

#define B_ 2048
#define N_ 256
#define R_ (B_*N_)
#define MU_ 0.1f
#define SIGMA_ 0.2f
#define TILE_M 64
#define GRID_MLP 256
#define ITERS (R_ / TILE_M / GRID_MLP)   // 32

typedef __attribute__((ext_vector_type(4))) float f32x4;
typedef __attribute__((ext_vector_type(2))) int   i32x2;
typedef __attribute__((ext_vector_type(8))) int   i32x8;

// ---- convert fW1/gW1 (256x256 f32, k-major) to fp8-e4m3 K=128 MFMA fragments ----
// word idx = (((ki*16 + ct)*64 + lane)*8 + q) ; byte j of lane block holds
// W1[k = ki*128 + (lane>>4)*32 + j][c = ct*16 + (lane&15)]  (A/B symmetric map)
__global__ void prep_weights(const float* __restrict__ fW1, const float* __restrict__ gW1,
                             unsigned int* __restrict__ wswz) {
    int idx = blockIdx.x * 256 + threadIdx.x;   // u32-word index, 16384 words per MLP
    if (idx >= 2 * 16384) return;
    int m = idx >> 14, wi = idx & 16383;
    int frag = wi >> 9;                 // ki*16 + ct
    int lane = (wi >> 3) & 63, q = wi & 7;
    int ki = frag >> 4, ct = frag & 15;
    int k = ki * 128 + (lane >> 4) * 32 + q * 4;
    int c = ct * 16 + (lane & 15);
    const float* W = m ? gW1 : fW1;
    float v0 = W[(k + 0) * 256 + c];
    float v1 = W[(k + 1) * 256 + c];
    float v2 = W[(k + 2) * 256 + c];
    float v3 = W[(k + 3) * 256 + c];
    int u = __builtin_amdgcn_cvt_pk_fp8_f32(v0, v1, 0, false);
    u = __builtin_amdgcn_cvt_pk_fp8_f32(v2, v3, u, true);
    wswz[idx] = (unsigned int)u;
}

// ---- trajectory via wave-parallel prefix-product scan: one wave per batch row ----
__global__ void traj_kernel(const float* __restrict__ ts, const float* __restrict__ x0,
                            const float* __restrict__ eps, float* __restrict__ xs,
                             float* __restrict__ fv) {
    int gid = blockIdx.x * 256 + threadIdx.x;
    int b = gid >> 6, lane = gid & 63;
    int n0 = lane * 4;

    float t0 = ts[n0], t1 = ts[n0 + 1], t2 = ts[n0 + 2], t3 = ts[n0 + 3];
    float t4 = (n0 + 4 < N_) ? ts[n0 + 4] : t3;          // lane 63: h3 = 0
    float h0 = t1 - t0, h1 = t2 - t1, h2 = t3 - t2, h3 = t4 - t3;
    float s0 = sqrtf(h0), s1 = sqrtf(h1), s2 = sqrtf(h2), s3 = sqrtf(h3);

    const float4* e4 = (const float4*)(eps + (size_t)(b * N_ + n0) * 2);
    float4 ea = e4[0], eb = e4[1];
    float f0a = 1.f + MU_ * h0 + SIGMA_ * (ea.x * s0);
    float f0b = 1.f + MU_ * h0 + SIGMA_ * (ea.y * s0);
    float f1a = 1.f + MU_ * h1 + SIGMA_ * (ea.z * s1);
    float f1b = 1.f + MU_ * h1 + SIGMA_ * (ea.w * s1);
    float f2a = 1.f + MU_ * h2 + SIGMA_ * (eb.x * s2);
    float f2b = 1.f + MU_ * h2 + SIGMA_ * (eb.y * s2);
    float f3a = 1.f + MU_ * h3 + SIGMA_ * (eb.z * s3);
    float f3b = 1.f + MU_ * h3 + SIGMA_ * (eb.w * s3);

    float Pa = f0a * f1a * f2a * f3a;
    float Pb = f0b * f1b * f2b * f3b;
    float Sa = Pa, Sb = Pb;
#pragma unroll
    for (int d = 1; d < 64; d <<= 1) {
        float va = __shfl_up(Sa, d);
        float vb = __shfl_up(Sb, d);
        if (lane >= d) { Sa *= va; Sb *= vb; }
    }
    float Ea = __shfl_up(Sa, 1);
    float Eb = __shfl_up(Sb, 1);
    if (lane == 0) { Ea = 1.f; Eb = 1.f; }

    float x0a = x0[2 * b], x0b = x0[2 * b + 1];
    float xa0 = x0a * Ea, xb0 = x0b * Eb;
    float xa1 = xa0 * f0a, xb1 = xb0 * f0b;
    float xa2 = xa1 * f1a, xb2 = xb1 * f1b;
    float xa3 = xa2 * f2a, xb3 = xb2 * f2b;

    float4* xsv = (float4*)(xs + (size_t)(b * N_ + n0) * 2);
    xsv[0] = make_float4(xa0, xb0, xa1, xb1);
    xsv[1] = make_float4(xa2, xb2, xa3, xb3);
    if (lane == 63) fv[b] = xa3 * xa3 + xb3 * xb3;
}

// ---- fused MLP: MX fp8 K=128, 1024-thread / 16-wave blocks ----
// r14 found the ONLY config with >1-block-equivalent residency (occupancy 21->41%)
// but spilled: allocator chose 64 VGPR (2-block heuristic) for a ~110-VGPR live set.
// r15's amdgpu_waves_per_eu(4,4) did NOT bind. Fix per r2->r3 evidence (launch_bounds
// 2nd arg DOES bind: (512,8)->32, (512,2)->128): __launch_bounds__(1024, 4) = 4 waves/EU
// = 16 waves/CU = 1 block -> VGPR budget 512/4 = 128. Live set fits, spill gone.
__global__ __launch_bounds__(1024, 4) void mlp_kernel(
        const float* __restrict__ ts, const float* __restrict__ eps, const float* __restrict__ xs,
        const unsigned int* __restrict__ wswz,
        const float* __restrict__ fW0, const float* __restrict__ fb0,
        const float* __restrict__ fb1, const float* __restrict__ fW2, const float* __restrict__ fb2,
        const float* __restrict__ gW0, const float* __restrict__ gb0,
        const float* __restrict__ gb1, const float* __restrict__ gW2, const float* __restrict__ gb2,
        float* __restrict__ Yout, float* __restrict__ zdot) {

    __shared__ __align__(16) unsigned char h0s[2][TILE_M * 256];   // fp8, 2 x 16KB, 8B swizzle
    __shared__ __align__(16) float4 sfx[TILE_M * ITERS];           // {t, x1, x2, -} 32KB
    __shared__ __align__(16) float2 sd[TILE_M * ITERS];            // {d0, d1} 16KB
    __shared__ __align__(16) float red[2][TILE_M][12];             // col-sums per wc, 6KB

    const int MLP = blockIdx.x & 1;
    const int bid = blockIdx.x >> 1;

    const float* W0 = MLP ? gW0 : fW0;
    const float* b0 = MLP ? gb0 : fb0;
    const float* b1 = MLP ? gb1 : fb1;
    const float* W2 = MLP ? gW2 : fW2;
    const float* b2 = MLP ? gb2 : fb2;
    float* outp     = MLP ? zdot : Yout;

    const int tid  = threadIdx.x;
    const int lane = tid & 63;
    const int w    = tid >> 6;       // wave 0..15
    const int wr   = w & 1;          // row half: rows [32wr, 32wr+32)
    const int wc   = w >> 1;         // col patch: cols [32wc, 32wc+32)
    const int arow = lane & 15;      // sample index within 16-row tile
    const int rg   = lane >> 4;      // k-block group / c-subgroup

    const int c0 = (tid & 63) * 4;   // layer0 col base (64 col-groups x 4)
    const int row0 = (tid >> 6) * 4; // layer0 row base (16 row-groups x 4)
    f32x4 w0t = *(const f32x4*)(W0 + c0);
    f32x4 w0x = *(const f32x4*)(W0 + 256 + c0);
    f32x4 w0y = *(const f32x4*)(W0 + 512 + c0);
    f32x4 w0bv = *(const f32x4*)(b0 + c0);

    // layer1 bias + layer2 weights resident in VGPRs (cols 32wc+16p+4rg+i)
    f32x4 bi0 = *(const f32x4*)(b1 + wc * 32 + 4 * rg);
    f32x4 bi1 = *(const f32x4*)(b1 + wc * 32 + 16 + 4 * rg);
    f32x4 w20v[2], w21v[2];
#pragma unroll
    for (int p = 0; p < 2; ++p) {
        int c = wc * 32 + p * 16 + 4 * rg;
        if (MLP) {
            f32x4 lo = *(const f32x4*)(W2 + 2 * c);
            f32x4 hi = *(const f32x4*)(W2 + 2 * c + 4);
            w20v[p] = (f32x4){lo[0], lo[2], hi[0], hi[2]};
            w21v[p] = (f32x4){lo[1], lo[3], hi[1], hi[3]};
        } else {
            w20v[p] = *(const f32x4*)(W2 + c);
            w21v[p] = (f32x4){0.f, 0.f, 0.f, 0.f};
        }
    }
    const float b20 = b2[0];
    const float b21 = MLP ? b2[1] : 0.f;

    // resident A-fragments of W1^T (fp8, K=128): 2 ki x 2 p x 8 VGPR = 32 VGPRs
    i32x8 afrag[2][2];
    {
        const i32x2* wsw2 = (const i32x2*)(wswz + MLP * 16384);
#pragma unroll
        for (int ki = 0; ki < 2; ++ki)
#pragma unroll
            for (int p = 0; p < 2; ++p) {
                int base = ((ki * 16 + (wc * 2 + p)) * 64 + lane) * 4;
                i32x2 a0 = wsw2[base], a1 = wsw2[base + 1], a2 = wsw2[base + 2], a3 = wsw2[base + 3];
                afrag[ki][p] = (i32x8){a0[0], a0[1], a1[0], a1[1], a2[0], a2[1], a3[0], a3[1]};
            }
    }

    // ---- preload ALL per-block sample data to LDS (coalesced, once) ----
#pragma unroll
    for (int q = 0; q < 2; ++q) {
        int s = q * 1024 + tid;                // 0..2047
        int it = s >> 6, i = s & 63;
        int r = (bid + it * GRID_MLP) * TILE_M + i;
        int n = r & (N_ - 1);
        float2 xv = ((const float2*)xs)[r];
        float tv = ts[n];
        sfx[s] = make_float4(tv, xv.x, xv.y, 0.f);
        if (MLP) {
            float sdt = (n < N_ - 1) ? sqrtf(ts[n + 1] - tv) : 0.f;
            float2 ev = ((const float2*)eps)[r];
            sd[s] = make_float2(ev.x * sdt, ev.y * sdt);
        }
    }
    __syncthreads();

    // layer0 tile 0 -> h0s[0] (4 rows x 4 cols per thread)
#pragma unroll
    for (int ii = 0; ii < 4; ++ii) {
        int r = row0 + ii;
        float4 v = sfx[r];
        f32x4 h;
#pragma unroll
        for (int j = 0; j < 4; ++j)
            h[j] = fmaxf(fmaf(v.x, w0t[j], fmaf(v.y, w0x[j], fmaf(v.z, w0y[j], w0bv[j]))), 0.f);
        int q = __builtin_amdgcn_cvt_pk_fp8_f32(h[0], h[1], 0, false);
        q = __builtin_amdgcn_cvt_pk_fp8_f32(h[2], h[3], q, true);
        int off = r * 256 + (c0 ^ ((r & 15) << 3));
        *(unsigned int*)(h0s[0] + off) = (unsigned int)q;
    }
    __syncthreads();

    for (int t = 0; t < ITERS; ++t) {
        const int sb = t & 1;

        // out-write for tile t-1 (only in-loop global op)
        if (t > 0 && tid < TILE_M) {
            const int pb = sb ^ 1;
            const float* rr = red[pb][tid];
            f32x4 v0 = *(const f32x4*)(rr + 0);
            f32x4 v1 = *(const f32x4*)(rr + 4);
            float s = ((v0[0] + v0[1]) + (v0[2] + v0[3])) + ((v1[0] + v1[1]) + (v1[2] + v1[3]));
            if (!MLP) s += b20;
            outp[(bid + (t - 1) * GRID_MLP) * TILE_M + tid] = s;
        }

        // MFMA(t) <- h0s[sb]: 2 ki x 2 rt x 2 p = 8 MX-scaled MFMA (K=128, scale=1.0)
        f32x4 acc[2][2];
#pragma unroll
        for (int rt = 0; rt < 2; ++rt) { acc[rt][0] = bi0; acc[rt][1] = bi1; }
        __builtin_amdgcn_s_setprio(1);
#pragma unroll
        for (int ki = 0; ki < 2; ++ki) {
#pragma unroll
            for (int rt = 0; rt < 2; ++rt) {
                int row = wr * 32 + rt * 16 + arow;
                const int rsw = (row & 15) << 3;
                const unsigned char* bp = h0s[sb] + row * 256;
                const int kb = ki * 128 + rg * 32;
                i32x2 q0 = *(const i32x2*)(bp + ((kb +  0) ^ rsw));
                i32x2 q1 = *(const i32x2*)(bp + ((kb +  8) ^ rsw));
                i32x2 q2 = *(const i32x2*)(bp + ((kb + 16) ^ rsw));
                i32x2 q3 = *(const i32x2*)(bp + ((kb + 24) ^ rsw));
                i32x8 bf = (i32x8){q0[0], q0[1], q1[0], q1[1], q2[0], q2[1], q3[0], q3[1]};
                acc[rt][0] = __builtin_amdgcn_mfma_scale_f32_16x16x128_f8f6f4(
                                 afrag[ki][0], bf, acc[rt][0], 0, 0, 0, 127, 0, 127);
                acc[rt][1] = __builtin_amdgcn_mfma_scale_f32_16x16x128_f8f6f4(
                                 afrag[ki][1], bf, acc[rt][1], 0, 0, 0, 127, 0, 127);
            }
        }
        __builtin_amdgcn_s_setprio(0);

        // epilogue: relu + dot(w2) per lane, rg-reduce via 2 shfl, red[row][wc]
#pragma unroll
        for (int rt = 0; rt < 2; ++rt) {
            float A0 = 0.f, A1 = 0.f;
#pragma unroll
            for (int p = 0; p < 2; ++p) {
#pragma unroll
                for (int i = 0; i < 4; ++i) {
                    float v = fmaxf(acc[rt][p][i], 0.f);
                    A0 = fmaf(v, w20v[p][i], A0);
                    if (MLP) A1 = fmaf(v, w21v[p][i], A1);
                }
            }
            A0 += __shfl_xor(A0, 16); A0 += __shfl_xor(A0, 32);
            if (MLP) { A1 += __shfl_xor(A1, 16); A1 += __shfl_xor(A1, 32); }
            if (rg == 0) {
                int row = wr * 32 + rt * 16 + arow;
                float rv;
                if (MLP) {
                    float2 dv = sd[t * TILE_M + row];
                    rv = fmaf(A1, dv.y, A0 * dv.x);
                    if (wc == 0) rv += fmaf(b21, dv.y, b20 * dv.x);
                } else {
                    rv = A0;
                }
                red[sb][row][wc] = rv;
            }
        }

        // layer0(t+1) -> h0s[sb^1] (LDS-resident samples only)
        if (t + 1 < ITERS) {
            const int sbase = (t + 1) * TILE_M;
#pragma unroll
            for (int ii = 0; ii < 4; ++ii) {
                int r = row0 + ii;
                float4 v = sfx[sbase + r];
                f32x4 h;
#pragma unroll
                for (int j = 0; j < 4; ++j)
                    h[j] = fmaxf(fmaf(v.x, w0t[j], fmaf(v.y, w0x[j], fmaf(v.z, w0y[j], w0bv[j]))), 0.f);
                int q = __builtin_amdgcn_cvt_pk_fp8_f32(h[0], h[1], 0, false);
                q = __builtin_amdgcn_cvt_pk_fp8_f32(h[2], h[3], q, true);
                int off = r * 256 + (c0 ^ ((r & 15) << 3));
                *(unsigned int*)(h0s[sb ^ 1] + off) = (unsigned int)q;
            }
        }
        __syncthreads();   // single per-tile barrier (LDS-only drain)
    }
    // final out-write (tile ITERS-1)
    if (tid < TILE_M) {
        const int pb = (ITERS - 1) & 1;
        const float* rr = red[pb][tid];
        f32x4 v0 = *(const f32x4*)(rr + 0);
        f32x4 v1 = *(const f32x4*)(rr + 4);
        float s = ((v0[0] + v0[1]) + (v0[2] + v0[3])) + ((v1[0] + v1[1]) + (v1[2] + v1[3]));
        if (!MLP) s += b20;
        outp[(bid + (ITERS - 1) * GRID_MLP) * TILE_M + tid] = s;
    }
}

// ---- loss: sum over r of (Y + Zdot - target)^2, /B ----
__global__ void loss_partial_kernel(const float* __restrict__ Yout, const float* __restrict__ fv,
                                    const float* __restrict__ zdot, float* __restrict__ partials) {
    __shared__ float wred[4];
    int tid = threadIdx.x;
    float s = 0.f;
    for (int r = blockIdx.x * 256 + tid; r < R_; r += gridDim.x * 256) {
        int n = r & (N_ - 1);
        float pred = Yout[r] + zdot[r];
        float target = (n == N_ - 1) ? fv[r >> 8] : Yout[r + 1];
        float d = pred - target;
        s = fmaf(d, d, s);
    }
#pragma unroll
    for (int m = 1; m < 64; m <<= 1) s += __shfl_xor(s, m);
    if ((tid & 63) == 0) wred[tid >> 6] = s;
    __syncthreads();
    if (tid == 0) partials[blockIdx.x] = wred[0] + wred[1] + wred[2] + wred[3];
}

__global__ void loss_final_kernel(const float* __restrict__ partials, float* __restrict__ out) {
    __shared__ float wred[4];
    int tid = threadIdx.x;
    float s = partials[tid] + partials[256 + tid] + partials[512 + tid] + partials[768 + tid];
#pragma unroll
    for (int m = 1; m < 64; m <<= 1) s += __shfl_xor(s, m);
    if ((tid & 63) == 0) wred[tid >> 6] = s;
    __syncthreads();
    if (tid == 0) out[0] = (wred[0] + wred[1] + wred[2] + wred[3]) * (1.0f / B_);
}

extern "C" void kernel_launch(void* const* d_in, const int* in_sizes, int n_in,
                              void* d_out, int out_size, void* d_ws, size_t ws_size,
                              hipStream_t stream) {
    const float* ts  = (const float*)d_in[0];
    const float* x0  = (const float*)d_in[1];
    const float* eps = (const float*)d_in[2];
    const float* fW0 = (const float*)d_in[3];
    const float* fb0 = (const float*)d_in[4];
    const float* fW1 = (const float*)d_in[5];
    const float* fb1 = (const float*)d_in[6];
    const float* fW2 = (const float*)d_in[7];
    const float* fb2 = (const float*)d_in[8];
    const float* gW0 = (const float*)d_in[9];
    const float* gb0 = (const float*)d_in[10];
    const float* gW1 = (const float*)d_in[11];
    const float* gb1 = (const float*)d_in[12];
    const float* gW2 = (const float*)d_in[13];
    const float* gb2 = (const float*)d_in[14];

    float* out  = (float*)d_out;
    float* Yout = out + 1;            // Y: (B,N,1) flat, row index r = b*N+n
    float* fv   = out + 1 + R_;       // final_value: (B,1)

    char* wsb = (char*)d_ws;
    float* xs           = (float*)wsb;                                          // B*N*2 f32 = 4MB
    unsigned int* wswz  = (unsigned int*)(wsb + (4 << 20));                     // fp8 K=128 frags, 128KB
    float* zdot         = (float*)(wsb + (4 << 20) + (256 << 10));              // 2MB
    float* partials     = (float*)(wsb + (4 << 20) + (256 << 10) + (2 << 20));  // 4KB

    hipLaunchKernelGGL(prep_weights, dim3(128), dim3(256), 0, stream, fW1, gW1, wswz);
    hipLaunchKernelGGL(traj_kernel, dim3(512), dim3(256), 0, stream, ts, x0, eps, xs, fv);
    hipLaunchKernelGGL(mlp_kernel, dim3(2 * GRID_MLP), dim3(1024), 0, stream,
                       ts, eps, xs, wswz,
                       fW0, fb0, fb1, fW2, fb2,
                       gW0, gb0, gb1, gW2, gb2, Yout, zdot);
    hipLaunchKernelGGL(loss_partial_kernel, dim3(1024), dim3(256), 0, stream, Yout, fv, zdot, partials);
    hipLaunchKernelGGL(loss_final_kernel, dim3(1), dim3(256), 0, stream, partials, out);
}

// Round 18
// 154.721 us; speedup vs baseline: 2.2178x; 2.2178x over previous
//
#include <hip/hip_runtime.h>
#include <math.h>

#define B_ 2048
#define N_ 256
#define R_ (B_*N_)
#define MU_ 0.1f
#define SIGMA_ 0.2f
#define TILE_M 64
#define GRID_MLP 512
#define ITERS (R_ / TILE_M / GRID_MLP)   // 16

typedef __attribute__((ext_vector_type(4))) float f32x4;
typedef __attribute__((ext_vector_type(2))) int   i32x2;
typedef __attribute__((ext_vector_type(8))) int   i32x8;

// ---- convert fW1/gW1 (256x256 f32, k-major) to fp8-e4m3 K=128 MFMA fragments ----
// word idx = (((ki*16 + ct)*64 + lane)*8 + q) ; byte j of lane block holds
// W1[k = ki*128 + (lane>>4)*32 + j][c = ct*16 + (lane&15)]  (A/B symmetric map)
__global__ void prep_weights(const float* __restrict__ fW1, const float* __restrict__ gW1,
                             unsigned int* __restrict__ wswz) {
    int idx = blockIdx.x * 256 + threadIdx.x;   // u32-word index, 16384 words per MLP
    if (idx >= 2 * 16384) return;
    int m = idx >> 14, wi = idx & 16383;
    int frag = wi >> 9;                 // ki*16 + ct
    int lane = (wi >> 3) & 63, q = wi & 7;
    int ki = frag >> 4, ct = frag & 15;
    int k = ki * 128 + (lane >> 4) * 32 + q * 4;
    int c = ct * 16 + (lane & 15);
    const float* W = m ? gW1 : fW1;
    float v0 = W[(k + 0) * 256 + c];
    float v1 = W[(k + 1) * 256 + c];
    float v2 = W[(k + 2) * 256 + c];
    float v3 = W[(k + 3) * 256 + c];
    int u = __builtin_amdgcn_cvt_pk_fp8_f32(v0, v1, 0, false);
    u = __builtin_amdgcn_cvt_pk_fp8_f32(v2, v3, u, true);
    wswz[idx] = (unsigned int)u;
}

// ---- trajectory via wave-parallel prefix-product scan: one wave per batch row ----
__global__ void traj_kernel(const float* __restrict__ ts, const float* __restrict__ x0,
                            const float* __restrict__ eps, float* __restrict__ xs,
                            float* __restrict__ fv) {
    int gid = blockIdx.x * 256 + threadIdx.x;
    int b = gid >> 6, lane = gid & 63;
    int n0 = lane * 4;

    float t0 = ts[n0], t1 = ts[n0 + 1], t2 = ts[n0 + 2], t3 = ts[n0 + 3];
    float t4 = (n0 + 4 < N_) ? ts[n0 + 4] : t3;          // lane 63: h3 = 0
    float h0 = t1 - t0, h1 = t2 - t1, h2 = t3 - t2, h3 = t4 - t3;
    float s0 = sqrtf(h0), s1 = sqrtf(h1), s2 = sqrtf(h2), s3 = sqrtf(h3);

    const float4* e4 = (const float4*)(eps + (size_t)(b * N_ + n0) * 2);
    float4 ea = e4[0], eb = e4[1];
    float f0a = 1.f + MU_ * h0 + SIGMA_ * (ea.x * s0);
    float f0b = 1.f + MU_ * h0 + SIGMA_ * (ea.y * s0);
    float f1a = 1.f + MU_ * h1 + SIGMA_ * (ea.z * s1);
    float f1b = 1.f + MU_ * h1 + SIGMA_ * (ea.w * s1);
    float f2a = 1.f + MU_ * h2 + SIGMA_ * (eb.x * s2);
    float f2b = 1.f + MU_ * h2 + SIGMA_ * (eb.y * s2);
    float f3a = 1.f + MU_ * h3 + SIGMA_ * (eb.z * s3);
    float f3b = 1.f + MU_ * h3 + SIGMA_ * (eb.w * s3);

    float Pa = f0a * f1a * f2a * f3a;
    float Pb = f0b * f1b * f2b * f3b;
    float Sa = Pa, Sb = Pb;
#pragma unroll
    for (int d = 1; d < 64; d <<= 1) {
        float va = __shfl_up(Sa, d);
        float vb = __shfl_up(Sb, d);
        if (lane >= d) { Sa *= va; Sb *= vb; }
    }
    float Ea = __shfl_up(Sa, 1);
    float Eb = __shfl_up(Sb, 1);
    if (lane == 0) { Ea = 1.f; Eb = 1.f; }

    float x0a = x0[2 * b], x0b = x0[2 * b + 1];
    float xa0 = x0a * Ea, xb0 = x0b * Eb;
    float xa1 = xa0 * f0a, xb1 = xb0 * f0b;
    float xa2 = xa1 * f1a, xb2 = xb1 * f1b;
    float xa3 = xa2 * f2a, xb3 = xb2 * f2b;

    float4* xsv = (float4*)(xs + (size_t)(b * N_ + n0) * 2);
    xsv[0] = make_float4(xa0, xb0, xa1, xb1);
    xsv[1] = make_float4(xa2, xb2, xa3, xb3);
    if (lane == 63) fv[b] = xa3 * xa3 + xb3 * xb3;
}

// ---- fused MLP: MX-scaled fp8 K=128 MFMA, LDS-resident samples (r13 config) ----
// Session-best structure. Merged f+g: grid 1024, MLP=blockIdx&1, bid=blockIdx>>1.
// TILE_M=64, ITERS=16, 512 threads / 8 waves, single barrier per tile.
// (1) B-frag reads = 4x ds_read_b64 with the 0-conflict 8B swizzle ((row&15)<<3);
// (2) samples packed float4/float2; (3) shuffle-free epilogue via red2[row][w*4+rg]
// (stride 36); (4) setprio around MFMA cluster.
__global__ __launch_bounds__(512) void mlp_kernel(
        const float* __restrict__ ts, const float* __restrict__ eps, const float* __restrict__ xs,
        const unsigned int* __restrict__ wswz,
        const float* __restrict__ fW0, const float* __restrict__ fb0,
        const float* __restrict__ fb1, const float* __restrict__ fW2, const float* __restrict__ fb2,
        const float* __restrict__ gW0, const float* __restrict__ gb0,
        const float* __restrict__ gb1, const float* __restrict__ gW2, const float* __restrict__ gb2,
        float* __restrict__ Yout, float* __restrict__ zdot) {

    __shared__ __align__(16) unsigned char h0s[2][TILE_M * 256];   // fp8, 2 x 16KB, 8B swizzle
    __shared__ __align__(16) float4 sfx[TILE_M * ITERS];           // {t, x1, x2, -} 16KB
    __shared__ __align__(16) float2 sd[TILE_M * ITERS];            // {d0, d1} 8KB
    __shared__ __align__(16) float red2[2][TILE_M][36];            // partials, 18KB

    const int MLP = blockIdx.x & 1;
    const int bid = blockIdx.x >> 1;

    const float* W0 = MLP ? gW0 : fW0;
    const float* b0 = MLP ? gb0 : fb0;
    const float* b1 = MLP ? gb1 : fb1;
    const float* W2 = MLP ? gW2 : fW2;
    const float* b2 = MLP ? gb2 : fb2;
    float* outp     = MLP ? zdot : Yout;

    const int tid  = threadIdx.x;
    const int lane = tid & 63;
    const int w    = tid >> 6;       // wave 0..7: cols [32w, 32w+32)
    const int arow = lane & 15;      // sample index within 16-row tile
    const int rg   = lane >> 4;      // k-block group / c-subgroup

    const int c0 = (tid & 63) * 4;   // layer0 col base
    const int row0 = (tid >> 6) * 8; // layer0 row base (8 rows/thread)
    f32x4 w0t = *(const f32x4*)(W0 + c0);
    f32x4 w0x = *(const f32x4*)(W0 + 256 + c0);
    f32x4 w0y = *(const f32x4*)(W0 + 512 + c0);
    f32x4 w0bv = *(const f32x4*)(b0 + c0);

    // layer1 bias + layer2 weights resident in VGPRs
    f32x4 bi0 = *(const f32x4*)(b1 + w * 32 + 4 * rg);
    f32x4 bi1 = *(const f32x4*)(b1 + w * 32 + 16 + 4 * rg);
    f32x4 w20v[2], w21v[2];
#pragma unroll
    for (int p = 0; p < 2; ++p) {
        int c = w * 32 + p * 16 + 4 * rg;
        if (MLP) {
            f32x4 lo = *(const f32x4*)(W2 + 2 * c);
            f32x4 hi = *(const f32x4*)(W2 + 2 * c + 4);
            w20v[p] = (f32x4){lo[0], lo[2], hi[0], hi[2]};
            w21v[p] = (f32x4){lo[1], lo[3], hi[1], hi[3]};
        } else {
            w20v[p] = *(const f32x4*)(W2 + c);
            w21v[p] = (f32x4){0.f, 0.f, 0.f, 0.f};
        }
    }
    const float b20 = b2[0];
    const float b21 = MLP ? b2[1] : 0.f;

    // resident A-fragments of W1^T (fp8, K=128): 2 ki x 2 ct x 8 VGPR = 32 VGPRs
    i32x8 afrag[2][2];
    {
        const i32x2* wsw2 = (const i32x2*)(wswz + MLP * 16384);
#pragma unroll
        for (int ki = 0; ki < 2; ++ki)
#pragma unroll
            for (int p = 0; p < 2; ++p) {
                int base = ((ki * 16 + (w * 2 + p)) * 64 + lane) * 4;
                i32x2 a0 = wsw2[base], a1 = wsw2[base + 1], a2 = wsw2[base + 2], a3 = wsw2[base + 3];
                afrag[ki][p] = (i32x8){a0[0], a0[1], a1[0], a1[1], a2[0], a2[1], a3[0], a3[1]};
            }
    }

    // ---- preload ALL per-block sample data to LDS (coalesced, once) ----
#pragma unroll
    for (int q = 0; q < 2; ++q) {
        int s = q * 512 + tid;                 // 0..1023
        int it = s >> 6, i = s & 63;
        int r = (bid + it * GRID_MLP) * TILE_M + i;
        int n = r & (N_ - 1);
        float2 xv = ((const float2*)xs)[r];
        float tv = ts[n];
        sfx[s] = make_float4(tv, xv.x, xv.y, 0.f);
        if (MLP) {
            float sdt = (n < N_ - 1) ? sqrtf(ts[n + 1] - tv) : 0.f;
            float2 ev = ((const float2*)eps)[r];
            sd[s] = make_float2(ev.x * sdt, ev.y * sdt);
        }
    }
    __syncthreads();

    // layer0 tile 0 -> h0s[0]
#pragma unroll
    for (int ii = 0; ii < 8; ++ii) {
        int r = row0 + ii;
        float4 v = sfx[r];
        f32x4 h;
#pragma unroll
        for (int j = 0; j < 4; ++j)
            h[j] = fmaxf(fmaf(v.x, w0t[j], fmaf(v.y, w0x[j], fmaf(v.z, w0y[j], w0bv[j]))), 0.f);
        int q = __builtin_amdgcn_cvt_pk_fp8_f32(h[0], h[1], 0, false);
        q = __builtin_amdgcn_cvt_pk_fp8_f32(h[2], h[3], q, true);
        int off = r * 256 + (c0 ^ ((r & 15) << 3));
        *(unsigned int*)(h0s[0] + off) = (unsigned int)q;
    }
    __syncthreads();

    for (int t = 0; t < ITERS; ++t) {
        const int sb = t & 1;

        // out-write for tile t-1 (only in-loop global op)
        if (t > 0 && tid < TILE_M) {
            const int pb = sb ^ 1;
            const float* rr = red2[pb][tid];
            float s = 0.f;
#pragma unroll
            for (int j = 0; j < 32; j += 4) {
                f32x4 v = *(const f32x4*)(rr + j);
                s += (v[0] + v[1]) + (v[2] + v[3]);
            }
            if (!MLP) s += b20;
            outp[(bid + (t - 1) * GRID_MLP) * TILE_M + tid] = s;
        }

        // MFMA(t) <- h0s[sb]: 2 ki x 4 rt x 2 p = 16 MX-scaled MFMA (K=128, scale=1.0)
        f32x4 acc[4][2];
#pragma unroll
        for (int rt = 0; rt < 4; ++rt) { acc[rt][0] = bi0; acc[rt][1] = bi1; }
        __builtin_amdgcn_s_setprio(1);
#pragma unroll
        for (int ki = 0; ki < 2; ++ki) {
#pragma unroll
            for (int rt = 0; rt < 4; ++rt) {
                int row = rt * 16 + arow;
                const int rsw = (row & 15) << 3;
                const unsigned char* bp = h0s[sb] + row * 256;
                const int kb = ki * 128 + rg * 32;
                i32x2 q0 = *(const i32x2*)(bp + ((kb +  0) ^ rsw));
                i32x2 q1 = *(const i32x2*)(bp + ((kb +  8) ^ rsw));
                i32x2 q2 = *(const i32x2*)(bp + ((kb + 16) ^ rsw));
                i32x2 q3 = *(const i32x2*)(bp + ((kb + 24) ^ rsw));
                i32x8 bf = (i32x8){q0[0], q0[1], q1[0], q1[1], q2[0], q2[1], q3[0], q3[1]};
                acc[rt][0] = __builtin_amdgcn_mfma_scale_f32_16x16x128_f8f6f4(
                                 afrag[ki][0], bf, acc[rt][0], 0, 0, 0, 127, 0, 127);
                acc[rt][1] = __builtin_amdgcn_mfma_scale_f32_16x16x128_f8f6f4(
                                 afrag[ki][1], bf, acc[rt][1], 0, 0, 0, 127, 0, 127);
            }
        }
        __builtin_amdgcn_s_setprio(0);

        // epilogue -> red2[sb] (per-lane partial; no cross-lane shuffles)
#pragma unroll
        for (int rt = 0; rt < 4; ++rt) {
            float A0 = 0.f, A1 = 0.f;
#pragma unroll
            for (int p = 0; p < 2; ++p) {
#pragma unroll
                for (int i = 0; i < 4; ++i) {
                    float v = fmaxf(acc[rt][p][i], 0.f);
                    A0 = fmaf(v, w20v[p][i], A0);
                    if (MLP) A1 = fmaf(v, w21v[p][i], A1);
                }
            }
            int row = rt * 16 + arow;
            float rv;
            if (MLP) {
                float2 dv = sd[t * TILE_M + row];
                rv = fmaf(A1, dv.y, A0 * dv.x);
                if (w == 0) rv += fmaf(b21, dv.y, b20 * dv.x);
            } else {
                rv = A0;
            }
            red2[sb][row][w * 4 + rg] = rv;
        }

        // layer0(t+1) -> h0s[sb^1] (LDS-resident samples only)
        if (t + 1 < ITERS) {
            const int sbase = (t + 1) * TILE_M;
#pragma unroll
            for (int ii = 0; ii < 8; ++ii) {
                int r = row0 + ii;
                float4 v = sfx[sbase + r];
                f32x4 h;
#pragma unroll
                for (int j = 0; j < 4; ++j)
                    h[j] = fmaxf(fmaf(v.x, w0t[j], fmaf(v.y, w0x[j], fmaf(v.z, w0y[j], w0bv[j]))), 0.f);
                int q = __builtin_amdgcn_cvt_pk_fp8_f32(h[0], h[1], 0, false);
                q = __builtin_amdgcn_cvt_pk_fp8_f32(h[2], h[3], q, true);
                int off = r * 256 + (c0 ^ ((r & 15) << 3));
                *(unsigned int*)(h0s[sb ^ 1] + off) = (unsigned int)q;
            }
        }
        __syncthreads();   // single per-tile barrier (LDS-only drain)
    }
    // final out-write (tile ITERS-1)
    if (tid < TILE_M) {
        const int pb = (ITERS - 1) & 1;
        const float* rr = red2[pb][tid];
        float s = 0.f;
#pragma unroll
        for (int j = 0; j < 32; j += 4) {
            f32x4 v = *(const f32x4*)(rr + j);
            s += (v[0] + v[1]) + (v[2] + v[3]);
        }
        if (!MLP) s += b20;
        outp[(bid + (ITERS - 1) * GRID_MLP) * TILE_M + tid] = s;
    }
}

// ---- loss: sum over r of (Y + Zdot - target)^2, /B ----
__global__ void loss_partial_kernel(const float* __restrict__ Yout, const float* __restrict__ fv,
                                    const float* __restrict__ zdot, float* __restrict__ partials) {
    __shared__ float wred[4];
    int tid = threadIdx.x;
    float s = 0.f;
    for (int r = blockIdx.x * 256 + tid; r < R_; r += gridDim.x * 256) {
        int n = r & (N_ - 1);
        float pred = Yout[r] + zdot[r];
        float target = (n == N_ - 1) ? fv[r >> 8] : Yout[r + 1];
        float d = pred - target;
        s = fmaf(d, d, s);
    }
#pragma unroll
    for (int m = 1; m < 64; m <<= 1) s += __shfl_xor(s, m);
    if ((tid & 63) == 0) wred[tid >> 6] = s;
    __syncthreads();
    if (tid == 0) partials[blockIdx.x] = wred[0] + wred[1] + wred[2] + wred[3];
}

__global__ void loss_final_kernel(const float* __restrict__ partials, float* __restrict__ out) {
    __shared__ float wred[4];
    int tid = threadIdx.x;
    float s = partials[tid] + partials[256 + tid] + partials[512 + tid] + partials[768 + tid];
#pragma unroll
    for (int m = 1; m < 64; m <<= 1) s += __shfl_xor(s, m);
    if ((tid & 63) == 0) wred[tid >> 6] = s;
    __syncthreads();
    if (tid == 0) out[0] = (wred[0] + wred[1] + wred[2] + wred[3]) * (1.0f / B_);
}

extern "C" void kernel_launch(void* const* d_in, const int* in_sizes, int n_in,
                              void* d_out, int out_size, void* d_ws, size_t ws_size,
                              hipStream_t stream) {
    const float* ts  = (const float*)d_in[0];
    const float* x0  = (const float*)d_in[1];
    const float* eps = (const float*)d_in[2];
    const float* fW0 = (const float*)d_in[3];
    const float* fb0 = (const float*)d_in[4];
    const float* fW1 = (const float*)d_in[5];
    const float* fb1 = (const float*)d_in[6];
    const float* fW2 = (const float*)d_in[7];
    const float* fb2 = (const float*)d_in[8];
    const float* gW0 = (const float*)d_in[9];
    const float* gb0 = (const float*)d_in[10];
    const float* gW1 = (const float*)d_in[11];
    const float* gb1 = (const float*)d_in[12];
    const float* gW2 = (const float*)d_in[13];
    const float* gb2 = (const float*)d_in[14];

    float* out  = (float*)d_out;
    float* Yout = out + 1;            // Y: (B,N,1) flat, row index r = b*N+n
    float* fv   = out + 1 + R_;       // final_value: (B,1)

    char* wsb = (char*)d_ws;
    float* xs           = (float*)wsb;                                          // B*N*2 f32 = 4MB
    unsigned int* wswz  = (unsigned int*)(wsb + (4 << 20));                     // fp8 K=128 frags, 128KB
    float* zdot         = (float*)(wsb + (4 << 20) + (256 << 10));              // 2MB
    float* partials     = (float*)(wsb + (4 << 20) + (256 << 10) + (2 << 20));  // 4KB

    hipLaunchKernelGGL(prep_weights, dim3(128), dim3(256), 0, stream, fW1, gW1, wswz);
    hipLaunchKernelGGL(traj_kernel, dim3(512), dim3(256), 0, stream, ts, x0, eps, xs, fv);
    hipLaunchKernelGGL(mlp_kernel, dim3(2 * GRID_MLP), dim3(512), 0, stream,
                       ts, eps, xs, wswz,
                       fW0, fb0, fb1, fW2, fb2,
                       gW0, gb0, gb1, gW2, gb2, Yout, zdot);
    hipLaunchKernelGGL(loss_partial_kernel, dim3(1024), dim3(256), 0, stream, Yout, fv, zdot, partials);
    hipLaunchKernelGGL(loss_final_kernel, dim3(1), dim3(256), 0, stream, partials, out);
}